// Round 1
// baseline (948.432 us; speedup 1.0000x reference)
//
#include <hip/hip_runtime.h>
#include <hip/hip_bf16.h>

#define V_SIZE 50257
#define V_PAD  50304   // 393 * 128
#define NDIM   768
#define NROWS  2048    // B*L
#define BM 128
#define BN 128
#define BK 32
#define KSTEPS (NDIM / BK)
#define LOG_V_F 10.824905119f
#define EPS_F   1e-12f

typedef __bf16 bf16x8 __attribute__((ext_vector_type(8)));
typedef float  f32x4  __attribute__((ext_vector_type(4)));

__device__ __forceinline__ void async16(const void* g, void* l) {
  __builtin_amdgcn_global_load_lds(
      (const __attribute__((address_space(1))) void*)g,
      (__attribute__((address_space(3))) void*)l, 16, 0, 0);
}

// Normalize spatial part of hyperboloid points to unit vectors (bf16),
// optionally emit r = arccosh(x0). One block (256 thr) per row.
__global__ __launch_bounds__(256)
void normalize_rows_k(const float* __restrict__ src,        // [nrows_src][769]
                      __hip_bfloat16* __restrict__ dst,     // [grid][768] bf16
                      float* __restrict__ r_out,            // [nrows_src] or null
                      int nrows_src)
{
  const int row = blockIdx.x;
  const int t = threadIdx.x;
  __shared__ float red[8];
  if (row >= nrows_src) {  // zero padding rows (masked out in epilogue anyway)
    __hip_bfloat16 z = __float2bfloat16(0.0f);
    dst[(size_t)row * NDIM + t]       = z;
    dst[(size_t)row * NDIM + t + 256] = z;
    dst[(size_t)row * NDIM + t + 512] = z;
    return;
  }
  const float* h = src + (size_t)row * (NDIM + 1);
  float v0 = h[1 + t], v1 = h[1 + t + 256], v2 = h[1 + t + 512];
  float ss = v0 * v0 + v1 * v1 + v2 * v2;
  #pragma unroll
  for (int m = 1; m < 64; m <<= 1) ss += __shfl_xor(ss, m, 64);
  const int w = t >> 6;
  if ((t & 63) == 0) red[w] = ss;
  __syncthreads();
  if (t == 0) {
    float tot = red[0] + red[1] + red[2] + red[3];
    red[4] = 1.0f / fmaxf(sqrtf(tot), 1e-12f);
    if (r_out) {
      float x0 = fmaxf(h[0], 1.0f + 1e-7f);
      r_out[row] = acoshf(x0);
    }
  }
  __syncthreads();
  const float inv = red[4];
  dst[(size_t)row * NDIM + t]       = __float2bfloat16(v0 * inv);
  dst[(size_t)row * NDIM + t + 256] = __float2bfloat16(v1 * inv);
  dst[(size_t)row * NDIM + t + 512] = __float2bfloat16(v2 * inv);
}

// Fused cos-logits GEMM (bf16 MFMA, m97 structure) + streaming KL epilogue.
// Per row accumulates sum_v exp(cos) (atomics); block-scalar sum of
// p*(log(clip(p)) - cos) into S_scalar.
__global__ __launch_bounds__(256, 2)
void fused_gemm_kl(const __hip_bfloat16* __restrict__ uS,   // [2048][768]
                   const __hip_bfloat16* __restrict__ uW,   // [V_PAD][768]
                   const float* __restrict__ p_teacher,     // [2048][V]
                   float* __restrict__ sum_exp,             // [2048], zeroed
                   float* __restrict__ S_scalar)            // [1], zeroed
{
  __shared__ __attribute__((aligned(16))) __hip_bfloat16 lA[BM * BK]; // [128][32]
  __shared__ __attribute__((aligned(16))) __hip_bfloat16 lB[BN * BK]; // [128][32]
  __shared__ float sred[4];

  const int t = threadIdx.x;
  const int lane = t & 63;
  const int w = t >> 6;
  const int wr = w >> 1, wc = w & 1;      // 2x2 waves over 128x128 tile
  const int rowBase = blockIdx.x * BM;    // 16 row tiles
  const int colBase = blockIdx.y * BN;    // 393 col tiles

  f32x4 acc[4][4];
  #pragma unroll
  for (int i = 0; i < 4; ++i)
    #pragma unroll
    for (int j = 0; j < 4; ++j) acc[i][j] = (f32x4){0.f, 0.f, 0.f, 0.f};

  // global_load_lds staging: LDS byte b = i*4096 + w*1024 + lane*16
  const char* gA = (const char*)uS;
  const char* gB = (const char*)uW;
  const int b0 = w * 1024 + lane * 16;
  const int r0 = b0 >> 6, kb0 = b0 & 63;
  const int b1 = 4096 + b0;
  const int r1 = b1 >> 6, kb1 = b1 & 63;
  const char* srcA0 = gA + (size_t)(rowBase + r0) * (NDIM * 2) + kb0;
  const char* srcA1 = gA + (size_t)(rowBase + r1) * (NDIM * 2) + kb1;
  const char* srcB0 = gB + (size_t)(colBase + r0) * (NDIM * 2) + kb0;
  const char* srcB1 = gB + (size_t)(colBase + r1) * (NDIM * 2) + kb1;
  char* ldsA0 = (char*)lA + w * 1024;
  char* ldsA1 = (char*)lA + 4096 + w * 1024;
  char* ldsB0 = (char*)lB + w * 1024;
  char* ldsB1 = (char*)lB + 4096 + w * 1024;

  for (int kk = 0; kk < KSTEPS; ++kk) {
    if (kk) __syncthreads();               // prev compute done before overwrite
    const size_t ko = (size_t)kk * (BK * 2);
    async16(srcA0 + ko, ldsA0);
    async16(srcA1 + ko, ldsA1);
    async16(srcB0 + ko, ldsB0);
    async16(srcB1 + ko, ldsB1);
    __syncthreads();                       // compiler drains vmcnt(0) here

    bf16x8 af[4], bfr[4];
    #pragma unroll
    for (int mi = 0; mi < 4; ++mi) {
      int arow = wr * 64 + mi * 16 + (lane & 15);
      af[mi] = *(const bf16x8*)((const char*)lA + arow * 64 + (lane >> 4) * 16);
    }
    #pragma unroll
    for (int ni = 0; ni < 4; ++ni) {
      int brow = wc * 64 + ni * 16 + (lane & 15);
      bfr[ni] = *(const bf16x8*)((const char*)lB + brow * 64 + (lane >> 4) * 16);
    }
    #pragma unroll
    for (int mi = 0; mi < 4; ++mi)
      #pragma unroll
      for (int ni = 0; ni < 4; ++ni)
        acc[mi][ni] = __builtin_amdgcn_mfma_f32_16x16x32_bf16(
            af[mi], bfr[ni], acc[mi][ni], 0, 0, 0);
  }

  // Epilogue. C/D layout (m89-verified): col = lane&15, row = (lane>>4)*4 + reg.
  float sacc = 0.0f;
  const int cgrp = lane >> 4;
  const int cidx = lane & 15;
  #pragma unroll
  for (int mi = 0; mi < 4; ++mi) {
    float esum[4] = {0.f, 0.f, 0.f, 0.f};
    const int row0 = rowBase + wr * 64 + mi * 16 + cgrp * 4;
    #pragma unroll
    for (int ni = 0; ni < 4; ++ni) {
      const int v = colBase + wc * 64 + ni * 16 + cidx;
      const bool valid = (v < V_SIZE);
      const float* prow = p_teacher + (size_t)row0 * V_SIZE + v;
      #pragma unroll
      for (int j = 0; j < 4; ++j) {
        float logit = acc[mi][ni][j];
        if (valid) {
          float p = prow[(size_t)j * V_SIZE];
          float lp = __logf(fmaxf(p, EPS_F));
          sacc = fmaf(p, lp - logit, sacc);
          esum[j] += __expf(logit);        // cos in [-1,1]: no max shift needed
        }
      }
    }
    #pragma unroll
    for (int j = 0; j < 4; ++j) {
      float e = esum[j];
      e += __shfl_xor(e, 1, 64);
      e += __shfl_xor(e, 2, 64);
      e += __shfl_xor(e, 4, 64);
      e += __shfl_xor(e, 8, 64);
      if (cidx == 0) atomicAdd(&sum_exp[row0 + j], e);
    }
  }
  #pragma unroll
  for (int m = 1; m < 64; m <<= 1) sacc += __shfl_xor(sacc, m, 64);
  if (lane == 0) sred[w] = sacc;
  __syncthreads();
  if (t == 0) atomicAdd(S_scalar, sred[0] + sred[1] + sred[2] + sred[3]);
}

// KL = (S + sum_rows log(sum_exp)) / NROWS ; plus radial terms -> 6 outputs.
__global__ __launch_bounds__(256)
void finalize_k(const float* __restrict__ sum_exp,
                const float* __restrict__ S_scalar,
                const float* __restrict__ r_s,
                const float* __restrict__ te,
                float* __restrict__ out)
{
  const int t = threadIdx.x;
  float lse = 0.f, sq = 0.f, rs = 0.f, rt = 0.f, hn = 0.f;
  for (int row = t; row < NROWS; row += 256) {
    lse += __logf(sum_exp[row]);
    float r = r_s[row];
    float h = fminf(fmaxf(te[row] / LOG_V_F, 0.0f), 1.0f);
    float rtar = 3.0f / (1.0f + expf(h));  // sigmoid(-h)*R_MAX
    sq += (r - rtar) * (r - rtar);
    rs += r; rt += rtar; hn += h;
  }
  #pragma unroll
  for (int m = 1; m < 64; m <<= 1) {
    lse += __shfl_xor(lse, m, 64);
    sq  += __shfl_xor(sq, m, 64);
    rs  += __shfl_xor(rs, m, 64);
    rt  += __shfl_xor(rt, m, 64);
    hn  += __shfl_xor(hn, m, 64);
  }
  __shared__ float red[5][4];
  const int w = t >> 6;
  if ((t & 63) == 0) { red[0][w]=lse; red[1][w]=sq; red[2][w]=rs; red[3][w]=rt; red[4][w]=hn; }
  __syncthreads();
  if (t == 0) {
    float L  = red[0][0]+red[0][1]+red[0][2]+red[0][3];
    float SQ = red[1][0]+red[1][1]+red[1][2]+red[1][3];
    float RS = red[2][0]+red[2][1]+red[2][2]+red[2][3];
    float RT = red[3][0]+red[3][1]+red[3][2]+red[3][3];
    float HN = red[4][0]+red[4][1]+red[4][2]+red[4][3];
    float kl = (S_scalar[0] + L) / (float)NROWS;  // l_angular (T^2 = 1)
    float l_rad = SQ / (float)NROWS;
    out[0] = kl + 0.1f * l_rad;
    out[1] = kl;
    out[2] = l_rad;
    out[3] = RS / (float)NROWS;
    out[4] = RT / (float)NROWS;
    out[5] = HN / (float)NROWS;
  }
}

extern "C" void kernel_launch(void* const* d_in, const int* in_sizes, int n_in,
                              void* d_out, int out_size, void* d_ws, size_t ws_size,
                              hipStream_t stream) {
  const float* h_student = (const float*)d_in[0];   // [2][1024][769]
  const float* W_vocab   = (const float*)d_in[1];   // [50257][769]
  const float* p_teacher = (const float*)d_in[2];   // [2][1024][50257]
  const float* te        = (const float*)d_in[3];   // [2][1024]
  float* out = (float*)d_out;

  char* ws = (char*)d_ws;
  __hip_bfloat16* uW = (__hip_bfloat16*)ws;
  size_t off = (size_t)V_PAD * NDIM * 2;            // 77.3 MB
  __hip_bfloat16* uS = (__hip_bfloat16*)(ws + off); off += (size_t)NROWS * NDIM * 2;
  float* r_s     = (float*)(ws + off); off += NROWS * 4;
  float* sum_exp = (float*)(ws + off); off += NROWS * 4;
  float* S_scalar = (float*)(ws + off);

  // zero accumulators (sum_exp and S_scalar are contiguous)
  hipMemsetAsync(sum_exp, 0, NROWS * 4 + 16, stream);

  normalize_rows_k<<<dim3(V_PAD), dim3(256), 0, stream>>>(W_vocab, uW, nullptr, V_SIZE);
  normalize_rows_k<<<dim3(NROWS), dim3(256), 0, stream>>>(h_student, uS, r_s, NROWS);
  fused_gemm_kl<<<dim3(NROWS / BM, V_PAD / BN), dim3(256), 0, stream>>>(
      uS, uW, p_teacher, sum_exp, S_scalar);
  finalize_k<<<1, 256, 0, stream>>>(sum_exp, S_scalar, r_s, te, out);
}

// Round 2
// 834.008 us; speedup vs baseline: 1.1372x; 1.1372x over previous
//
#include <hip/hip_runtime.h>
#include <hip/hip_bf16.h>

#define V_SIZE 50257
#define V_PAD  50304   // 393 * 128
#define NDIM   768
#define NROWS  2048    // B*L
#define BM 128
#define BN 128
#define BK 32
#define KSTEPS (NDIM / BK)   // 24
#define LOG_V_F 10.824905119f
#define EPS_F   1e-12f

typedef __bf16 bf16x8 __attribute__((ext_vector_type(8)));
typedef float  f32x4  __attribute__((ext_vector_type(4)));

__device__ __forceinline__ void async16(const void* g, void* l) {
  __builtin_amdgcn_global_load_lds(
      (const __attribute__((address_space(1))) void*)g,
      (__attribute__((address_space(3))) void*)l, 16, 0, 0);
}

// Wave-per-row normalize: 4 rows per 256-thread block, no __syncthreads.
// Reads [nrows_src][769] f32, writes [nrows_dst][768] bf16 (pad rows zeroed),
// optional r = arccosh(x0).
__global__ __launch_bounds__(256)
void normalize_rows_wave(const float* __restrict__ src,
                         __hip_bfloat16* __restrict__ dst,
                         float* __restrict__ r_out,
                         int nrows_src, int nrows_dst)
{
  const int wid = blockIdx.x * 4 + (threadIdx.x >> 6);
  const int lane = threadIdx.x & 63;
  if (wid >= nrows_dst) return;
  __hip_bfloat16* drow = dst + (size_t)wid * NDIM;
  if (wid >= nrows_src) {              // zero padding rows
    #pragma unroll
    for (int s = 0; s < 12; ++s) drow[s * 64 + lane] = __float2bfloat16(0.0f);
    return;
  }
  const float* h = src + (size_t)wid * (NDIM + 1);
  float v[12];
  float ss = 0.0f;
  #pragma unroll
  for (int s = 0; s < 12; ++s) {       // coalesced: 256B per wave-load
    v[s] = h[1 + s * 64 + lane];
    ss = fmaf(v[s], v[s], ss);
  }
  #pragma unroll
  for (int m = 1; m < 64; m <<= 1) ss += __shfl_xor(ss, m, 64);
  const float inv = 1.0f / fmaxf(sqrtf(ss), 1e-12f);
  if (r_out != nullptr && lane == 0)
    r_out[wid] = acoshf(fmaxf(h[0], 1.0f + 1e-7f));
  #pragma unroll
  for (int s = 0; s < 12; ++s)         // coalesced: 128B per wave-store
    drow[s * 64 + lane] = __float2bfloat16(v[s] * inv);
}

// Fused cos-logits GEMM (bf16 MFMA, m97 structure) + streaming KL epilogue
// with register-prefetched p_teacher (first batch overlapped under the
// peeled final K-iteration via raw s_barrier + counted vmcnt).
__global__ __launch_bounds__(256, 2)
void fused_gemm_kl(const __hip_bfloat16* __restrict__ uS,   // [2048][768]
                   const __hip_bfloat16* __restrict__ uW,   // [V_PAD][768]
                   const float* __restrict__ p_teacher,     // [2048][V]
                   float* __restrict__ sum_exp,             // [2048], zeroed
                   float* __restrict__ S_scalar)            // [1], zeroed
{
  __shared__ __attribute__((aligned(16))) __hip_bfloat16 lA[BM * BK]; // [128][32]
  __shared__ __attribute__((aligned(16))) __hip_bfloat16 lB[BN * BK]; // [128][32]
  __shared__ float sred[4];

  const int t = threadIdx.x;
  const int lane = t & 63;
  const int w = t >> 6;
  const int wr = w >> 1, wc = w & 1;      // 2x2 waves over 128x128 tile
  const int rowBase = blockIdx.x * BM;    // 16 row tiles
  const int colBase = blockIdx.y * BN;    // 393 col tiles

  f32x4 acc[4][4];
  #pragma unroll
  for (int i = 0; i < 4; ++i)
    #pragma unroll
    for (int j = 0; j < 4; ++j) acc[i][j] = (f32x4){0.f, 0.f, 0.f, 0.f};

  // global_load_lds staging: LDS byte b = i*4096 + w*1024 + lane*16
  const char* gA = (const char*)uS;
  const char* gB = (const char*)uW;
  const int b0 = w * 1024 + lane * 16;
  const int r0 = b0 >> 6, kb0 = b0 & 63;
  const int b1 = 4096 + b0;
  const int r1 = b1 >> 6, kb1 = b1 & 63;
  const char* srcA0 = gA + (size_t)(rowBase + r0) * (NDIM * 2) + kb0;
  const char* srcA1 = gA + (size_t)(rowBase + r1) * (NDIM * 2) + kb1;
  const char* srcB0 = gB + (size_t)(colBase + r0) * (NDIM * 2) + kb0;
  const char* srcB1 = gB + (size_t)(colBase + r1) * (NDIM * 2) + kb1;
  char* ldsA0 = (char*)lA + w * 1024;
  char* ldsA1 = (char*)lA + 4096 + w * 1024;
  char* ldsB0 = (char*)lB + w * 1024;
  char* ldsB1 = (char*)lB + 4096 + w * 1024;

  auto stage = [&](int kk) {
    const size_t ko = (size_t)kk * (BK * 2);
    async16(srcA0 + ko, ldsA0);
    async16(srcA1 + ko, ldsA1);
    async16(srcB0 + ko, ldsB0);
    async16(srcB1 + ko, ldsB1);
  };
  auto compute = [&]() {
    bf16x8 af[4], bfr[4];
    #pragma unroll
    for (int mi = 0; mi < 4; ++mi) {
      int arow = wr * 64 + mi * 16 + (lane & 15);
      af[mi] = *(const bf16x8*)((const char*)lA + arow * 64 + (lane >> 4) * 16);
    }
    #pragma unroll
    for (int ni = 0; ni < 4; ++ni) {
      int brow = wc * 64 + ni * 16 + (lane & 15);
      bfr[ni] = *(const bf16x8*)((const char*)lB + brow * 64 + (lane >> 4) * 16);
    }
    #pragma unroll
    for (int mi = 0; mi < 4; ++mi)
      #pragma unroll
      for (int ni = 0; ni < 4; ++ni)
        acc[mi][ni] = __builtin_amdgcn_mfma_f32_16x16x32_bf16(
            af[mi], bfr[ni], acc[mi][ni], 0, 0, 0);
  };

  for (int kk = 0; kk < KSTEPS - 1; ++kk) {
    if (kk) __syncthreads();             // prev compute done before overwrite
    stage(kk);
    __syncthreads();                     // compiler drains vmcnt(0) here
    compute();
  }

  // Epilogue indices. C/D layout: col = lane&15, row = (lane>>4)*4 + reg.
  const int cgrp = lane >> 4;
  const int cidx = lane & 15;
  float vmaskf[4];
  int   vcol[4];
  #pragma unroll
  for (int ni = 0; ni < 4; ++ni) {
    int v = colBase + wc * 64 + ni * 16 + cidx;
    vmaskf[ni] = (v < V_SIZE) ? 1.0f : 0.0f;
    vcol[ni]   = (v < V_SIZE) ? v : (V_SIZE - 1);  // clamp: stay in-bounds
  }
  auto pload = [&](int mi, float* pr) {
    const int row0 = rowBase + wr * 64 + mi * 16 + cgrp * 4;
    #pragma unroll
    for (int ni = 0; ni < 4; ++ni) {
      const float* pp = p_teacher + (size_t)row0 * V_SIZE + vcol[ni];
      #pragma unroll
      for (int j = 0; j < 4; ++j) pr[ni * 4 + j] = pp[(size_t)j * V_SIZE];
    }
  };

  float prA[16], prB[16];

  // Peeled final K-iteration: stage, then issue 16 p-loads, wait only the
  // 4 staging loads (vmcnt(16)), raw barrier, compute with p still in flight.
  __syncthreads();
  stage(KSTEPS - 1);
  __builtin_amdgcn_sched_barrier(0);     // pin: p-loads AFTER the 4 async16
  pload(0, prA);
  __builtin_amdgcn_sched_barrier(0);
  asm volatile("s_waitcnt vmcnt(16)" ::: "memory");  // 4 oldest (staging) done
  __builtin_amdgcn_s_barrier();
  __builtin_amdgcn_sched_barrier(0);     // pin: ds_reads after barrier
  compute();

  float sacc = 0.0f;
  #pragma unroll
  for (int mi = 0; mi < 4; ++mi) {
    float* cur = (mi & 1) ? prB : prA;   // static after unroll
    float* nxt = (mi & 1) ? prA : prB;
    if (mi < 3) pload(mi + 1, nxt);      // next batch flies under exp/log
    const int row0 = rowBase + wr * 64 + mi * 16 + cgrp * 4;
    float esum[4] = {0.f, 0.f, 0.f, 0.f};
    #pragma unroll
    for (int ni = 0; ni < 4; ++ni) {
      const float m = vmaskf[ni];
      #pragma unroll
      for (int j = 0; j < 4; ++j) {
        float logit = acc[mi][ni][j];
        float p = cur[ni * 4 + j] * m;   // masked cols contribute exactly 0
        sacc = fmaf(p, __logf(fmaxf(p, EPS_F)) - logit, sacc);
        esum[j] = fmaf(m, __expf(logit), esum[j]);  // cos in [-1,1]: no shift
      }
    }
    #pragma unroll
    for (int j = 0; j < 4; ++j) {
      float e = esum[j];
      e += __shfl_xor(e, 1, 64);
      e += __shfl_xor(e, 2, 64);
      e += __shfl_xor(e, 4, 64);
      e += __shfl_xor(e, 8, 64);
      if (cidx == 0) atomicAdd(&sum_exp[row0 + j], e);
    }
  }
  #pragma unroll
  for (int m = 1; m < 64; m <<= 1) sacc += __shfl_xor(sacc, m, 64);
  if (lane == 0) sred[w] = sacc;
  __syncthreads();
  if (t == 0) atomicAdd(S_scalar, sred[0] + sred[1] + sred[2] + sred[3]);
}

// KL = (S + sum_rows log(sum_exp)) / NROWS ; plus radial terms -> 6 outputs.
__global__ __launch_bounds__(256)
void finalize_k(const float* __restrict__ sum_exp,
                const float* __restrict__ S_scalar,
                const float* __restrict__ r_s,
                const float* __restrict__ te,
                float* __restrict__ out)
{
  const int t = threadIdx.x;
  float lse = 0.f, sq = 0.f, rs = 0.f, rt = 0.f, hn = 0.f;
  for (int row = t; row < NROWS; row += 256) {
    lse += __logf(sum_exp[row]);
    float r = r_s[row];
    float h = fminf(fmaxf(te[row] / LOG_V_F, 0.0f), 1.0f);
    float rtar = 3.0f / (1.0f + expf(h));  // sigmoid(-h)*R_MAX
    sq += (r - rtar) * (r - rtar);
    rs += r; rt += rtar; hn += h;
  }
  #pragma unroll
  for (int m = 1; m < 64; m <<= 1) {
    lse += __shfl_xor(lse, m, 64);
    sq  += __shfl_xor(sq, m, 64);
    rs  += __shfl_xor(rs, m, 64);
    rt  += __shfl_xor(rt, m, 64);
    hn  += __shfl_xor(hn, m, 64);
  }
  __shared__ float red[5][4];
  const int w = t >> 6;
  if ((t & 63) == 0) { red[0][w]=lse; red[1][w]=sq; red[2][w]=rs; red[3][w]=rt; red[4][w]=hn; }
  __syncthreads();
  if (t == 0) {
    float L  = red[0][0]+red[0][1]+red[0][2]+red[0][3];
    float SQ = red[1][0]+red[1][1]+red[1][2]+red[1][3];
    float RS = red[2][0]+red[2][1]+red[2][2]+red[2][3];
    float RT = red[3][0]+red[3][1]+red[3][2]+red[3][3];
    float HN = red[4][0]+red[4][1]+red[4][2]+red[4][3];
    float kl = (S_scalar[0] + L) / (float)NROWS;  // l_angular (T^2 = 1)
    float l_rad = SQ / (float)NROWS;
    out[0] = kl + 0.1f * l_rad;
    out[1] = kl;
    out[2] = l_rad;
    out[3] = RS / (float)NROWS;
    out[4] = RT / (float)NROWS;
    out[5] = HN / (float)NROWS;
  }
}

extern "C" void kernel_launch(void* const* d_in, const int* in_sizes, int n_in,
                              void* d_out, int out_size, void* d_ws, size_t ws_size,
                              hipStream_t stream) {
  const float* h_student = (const float*)d_in[0];   // [2][1024][769]
  const float* W_vocab   = (const float*)d_in[1];   // [50257][769]
  const float* p_teacher = (const float*)d_in[2];   // [2][1024][50257]
  const float* te        = (const float*)d_in[3];   // [2][1024]
  float* out = (float*)d_out;

  char* ws = (char*)d_ws;
  __hip_bfloat16* uW = (__hip_bfloat16*)ws;
  size_t off = (size_t)V_PAD * NDIM * 2;            // 77.3 MB
  __hip_bfloat16* uS = (__hip_bfloat16*)(ws + off); off += (size_t)NROWS * NDIM * 2;
  float* r_s     = (float*)(ws + off); off += NROWS * 4;
  float* sum_exp = (float*)(ws + off); off += NROWS * 4;
  float* S_scalar = (float*)(ws + off);

  // zero accumulators (sum_exp and S_scalar are contiguous)
  hipMemsetAsync(sum_exp, 0, NROWS * 4 + 16, stream);

  normalize_rows_wave<<<dim3(V_PAD / 4), dim3(256), 0, stream>>>(
      W_vocab, uW, nullptr, V_SIZE, V_PAD);
  normalize_rows_wave<<<dim3(NROWS / 4), dim3(256), 0, stream>>>(
      h_student, uS, r_s, NROWS, NROWS);
  fused_gemm_kl<<<dim3(NROWS / BM, V_PAD / BN), dim3(256), 0, stream>>>(
      uS, uW, p_teacher, sum_exp, S_scalar);
  finalize_k<<<1, 256, 0, stream>>>(sum_exp, S_scalar, r_s, te, out);
}